// Round 5
// baseline (68.361 us; speedup 1.0000x reference)
//
#include <hip/hip_runtime.h>
#include <stdint.h>

// (N,T,F)=(128,8192,8), WS=16, E=256 -> nw=512, keep=205, mask=307
#define NB     128
#define TLEN   8192
#define FD     8
#define KD     128          // WS*F (GEMM K)
#define NWIN   512
#define ED     256
#define NKEEP  205
#define NMASK  307

// float32-element offsets in the concatenated output tuple
#define OFF_VIS  0UL
#define OFF_TGT  6717440UL        // + 128*205*256
#define OFF_MSK  16777216UL       // + 128*307*256
#define OFF_VIDX 26836992UL       // + 128*307*256
#define OFF_MIDX 26863232UL       // + 128*205

typedef __attribute__((ext_vector_type(8))) short bf16x8;
typedef __attribute__((ext_vector_type(4))) float f32x4;

static __device__ __forceinline__ unsigned short f2bf(float x) {
  union { float f; unsigned int u; } v; v.f = x;
  unsigned int r = v.u + 0x7fffu + ((v.u >> 16) & 1u);   // RNE
  return (unsigned short)(r >> 16);
}

// emb = flat @ W^T + b + pos_embed[win], rows produced in perm order so the
// visible/target writes are contiguous; temps rows are gathered (512B each).
// Block = 256 threads (4 waves). Wave wv owns features [wv*64, wv*64+64) with
// W staged in registers; block processes 4 slot-tiles of 16 slots for one n.
__global__ __launch_bounds__(256) void emb_kernel(
    const float* __restrict__ temps, const float* __restrict__ W,
    const float* __restrict__ b, const float* __restrict__ pos,
    const int* __restrict__ perm, float* __restrict__ out)
{
  const int tid  = threadIdx.x;
  const int lane = tid & 63;
  const int wv   = tid >> 6;     // 0..3
  const int l15  = lane & 15;
  const int lhi  = lane >> 4;    // 0..3

  const int n  = blockIdx.x >> 3;        // 8 blocks per batch row
  const int t0 = (blockIdx.x & 7) * 4;   // 4 slot-tiles per block
  const int e0 = wv * 64;

  // W fragments: e = e0+j*16+l15 (B-col), k = kk*32 + lhi*8 + i
  bf16x8 wb[4][4];
  float  bb[4];
  #pragma unroll
  for (int j = 0; j < 4; ++j) {
    const int e = e0 + j * 16 + l15;
    bb[j] = b[e];
    const float* wrow = W + (size_t)e * KD + lhi * 8;
    #pragma unroll
    for (int kk = 0; kk < 4; ++kk) {
      f32x4 w0 = *(const f32x4*)(wrow + kk * 32);
      f32x4 w1 = *(const f32x4*)(wrow + kk * 32 + 4);
      bf16x8 f;
      f[0] = (short)f2bf(w0[0]); f[1] = (short)f2bf(w0[1]);
      f[2] = (short)f2bf(w0[2]); f[3] = (short)f2bf(w0[3]);
      f[4] = (short)f2bf(w1[0]); f[5] = (short)f2bf(w1[1]);
      f[6] = (short)f2bf(w1[2]); f[7] = (short)f2bf(w1[3]);
      wb[j][kk] = f;
    }
  }

  const float* tbase = temps + (size_t)n * (TLEN * FD);
  const int*   pbase = perm + n * NWIN;
  const f32x4  zero  = {0.f, 0.f, 0.f, 0.f};

  for (int t = t0; t < t0 + 4; ++t) {
    const int s0 = t * 16;
    // A-row gather: lane's l15 = A row (slot within tile)
    const int awin = pbase[s0 + l15] & (NWIN - 1);
    const float* arow = tbase + (size_t)awin * KD + lhi * 8;

    f32x4 acc[4];
    acc[0] = zero; acc[1] = zero; acc[2] = zero; acc[3] = zero;

    #pragma unroll
    for (int kk = 0; kk < 4; ++kk) {
      f32x4 a0 = *(const f32x4*)(arow + kk * 32);
      f32x4 a1 = *(const f32x4*)(arow + kk * 32 + 4);
      bf16x8 a;
      a[0] = (short)f2bf(a0[0]); a[1] = (short)f2bf(a0[1]);
      a[2] = (short)f2bf(a0[2]); a[3] = (short)f2bf(a0[3]);
      a[4] = (short)f2bf(a1[0]); a[5] = (short)f2bf(a1[1]);
      a[6] = (short)f2bf(a1[2]); a[7] = (short)f2bf(a1[3]);
      #pragma unroll
      for (int j = 0; j < 4; ++j)
        acc[j] = __builtin_amdgcn_mfma_f32_16x16x32_bf16(a, wb[j][kk], acc[j], 0, 0, 0);
    }

    // C/D layout (HW-verified): row(slot) = lhi*4 + r, col(feature) = l15
    #pragma unroll
    for (int r = 0; r < 4; ++r) {
      const int slot = s0 + lhi * 4 + r;
      const int wr   = pbase[slot] & (NWIN - 1);
      size_t obase;
      if (slot < NKEEP) obase = OFF_VIS + (size_t)(n * NKEEP + slot) * ED;
      else              obase = OFF_TGT + (size_t)(n * NMASK + (slot - NKEEP)) * ED;
      const float* prow = pos + (size_t)wr * ED + e0 + l15;
      #pragma unroll
      for (int j = 0; j < 4; ++j)
        out[obase + (size_t)(e0 + j * 16 + l15)] = acc[j][r] + bb[j] + prow[j * 16];
    }
  }
}

// masked_input[n][j][e] = mask_token[e] + pos_embed[m_idx[n][j]][e]
// one thread = 2 consecutive e (8B store)
__global__ __launch_bounds__(256) void masked_kernel(
    const float* __restrict__ mask_token, const float* __restrict__ pos,
    const int* __restrict__ perm, float* __restrict__ out)
{
  const int idx  = blockIdx.x * 256 + threadIdx.x;   // N*NMASK*128 total
  const int half = idx & 127;
  const int row  = idx >> 7;                          // n*NMASK + j
  if (row >= NB * NMASK) return;
  const int n = row / NMASK;
  const int j = row - n * NMASK;
  const int m = perm[n * NWIN + NKEEP + j] & (NWIN - 1);
  const int e = half * 2;
  const float2 mt = *(const float2*)(mask_token + e);
  const float2 pe = *(const float2*)(pos + (size_t)m * ED + e);
  float2 o; o.x = mt.x + pe.x; o.y = mt.y + pe.y;
  *(float2*)(out + OFF_MSK + (size_t)row * ED + e) = o;
}

// v_idx / m_idx as float32 values
__global__ void idx_kernel(const int* __restrict__ perm, float* __restrict__ out)
{
  const int n = blockIdx.x;
  const int s = threadIdx.x;    // 0..511
  const int p = perm[n * NWIN + s] & (NWIN - 1);
  const float v = (float)p;
  if (s < NKEEP) out[OFF_VIDX + (size_t)n * NKEEP + s] = v;
  else           out[OFF_MIDX + (size_t)n * NMASK + (s - NKEEP)] = v;
}

extern "C" void kernel_launch(void* const* d_in, const int* in_sizes, int n_in,
                              void* d_out, int out_size, void* d_ws, size_t ws_size,
                              hipStream_t stream) {
  // Identify inputs by flat size (sizes distinct except b/mask_token; b first).
  int i_temps = 0, i_W = 1, i_b = 2, i_mt = 3, i_pos = 4, i_perm = 5;
  int small[2] = {-1, -1}; int nsmall = 0;
  for (int i = 0; i < n_in; ++i) {
    const int s = in_sizes[i];
    if (s == NB * TLEN * FD)        i_temps = i;
    else if (s == ED * KD)          i_W = i;
    else if (s == 1024 * ED)        i_pos = i;
    else if (s == NB * NWIN)        i_perm = i;
    else if (s == ED && nsmall < 2) small[nsmall++] = i;
  }
  if (nsmall == 2) { i_b = small[0]; i_mt = small[1]; }

  const float* temps      = (const float*)d_in[i_temps];
  const float* W          = (const float*)d_in[i_W];
  const float* b          = (const float*)d_in[i_b];
  const float* mask_token = (const float*)d_in[i_mt];
  const float* pos        = (const float*)d_in[i_pos];
  const int*   perm       = (const int*)d_in[i_perm];
  float* out = (float*)d_out;

  emb_kernel<<<dim3(1024), dim3(256), 0, stream>>>(temps, W, b, pos, perm, out);
  masked_kernel<<<dim3((NB * NMASK * 128 + 255) / 256), dim3(256), 0, stream>>>(
      mask_token, pos, perm, out);
  idx_kernel<<<dim3(NB), dim3(NWIN), 0, stream>>>(perm, out);
}

// Round 6
// 59.351 us; speedup vs baseline: 1.1518x; 1.1518x over previous
//
#include <hip/hip_runtime.h>
#include <stdint.h>

// (N,T,F)=(128,8192,8), WS=16, E=256 -> nw=512, keep=205, mask=307
#define NB     128
#define TLEN   8192
#define FD     8
#define KD     128          // WS*F (GEMM K)
#define NWIN   512
#define ED     256
#define NKEEP  205
#define NMASK  307

// float32-element offsets in the concatenated output tuple
#define OFF_VIS  0UL
#define OFF_TGT  6717440UL        // + 128*205*256
#define OFF_MSK  16777216UL       // + 128*307*256
#define OFF_VIDX 26836992UL       // + 128*307*256
#define OFF_MIDX 26863232UL       // + 128*205

#define ASTRIDE 136   // ushort per A-tile row (128 + 8 pad) -> 272B stride
#define ESTRIDE 68    // float per E row (64 + 4 pad) -> 272B stride

typedef __attribute__((ext_vector_type(8))) short bf16x8;
typedef __attribute__((ext_vector_type(4))) float f32x4;
typedef __attribute__((ext_vector_type(4))) unsigned int u32x4;

static __device__ __forceinline__ unsigned short f2bf(float x) {
  union { float f; unsigned int u; } v; v.f = x;
  unsigned int r = v.u + 0x7fffu + ((v.u >> 16) & 1u);   // RNE
  return (unsigned short)(r >> 16);
}
static __device__ __forceinline__ unsigned int pack2(float a, float b) {
  return (unsigned int)f2bf(a) | ((unsigned int)f2bf(b) << 16);
}

// emb = flat @ W^T + b + pos_embed[win], rows in perm order (contiguous
// vis/tgt stores, gathered temps rows). Block = 256 thr (4 waves), 32 slots
// (2 MFMA tiles of 16), A-tile staged once per block in LDS (bf16),
// double-buffered; W frags in registers (wave owns 64 features).
__global__ __launch_bounds__(256) void emb_kernel(
    const float* __restrict__ temps, const float* __restrict__ W,
    const float* __restrict__ b, const float* __restrict__ pos,
    const int* __restrict__ perm, float* __restrict__ out)
{
  __shared__ __align__(16) unsigned short Abuf[2][16][ASTRIDE];
  __shared__ __align__(16) float Ebuf[4][16][ESTRIDE];

  const int tid  = threadIdx.x;
  const int lane = tid & 63;
  const int wv   = tid >> 6;     // 0..3
  const int l15  = lane & 15;
  const int lhi  = lane >> 4;    // 0..3

  const int n  = blockIdx.x >> 4;         // 16 blocks per batch row
  const int s0 = (blockIdx.x & 15) * 32;  // 32 slots per block
  const int e0 = wv * 64;

  // W fragments: e = e0+j*16+l15 (B-col), k = kk*32 + lhi*8 + i
  bf16x8 wb[4][4];
  float  bb[4];
  #pragma unroll
  for (int j = 0; j < 4; ++j) {
    const int e = e0 + j * 16 + l15;
    bb[j] = b[e];
    const float* wrow = W + (size_t)e * KD + lhi * 8;
    #pragma unroll
    for (int kk = 0; kk < 4; ++kk) {
      f32x4 w0 = *(const f32x4*)(wrow + kk * 32);
      f32x4 w1 = *(const f32x4*)(wrow + kk * 32 + 4);
      bf16x8 f;
      f[0] = (short)f2bf(w0[0]); f[1] = (short)f2bf(w0[1]);
      f[2] = (short)f2bf(w0[2]); f[3] = (short)f2bf(w0[3]);
      f[4] = (short)f2bf(w1[0]); f[5] = (short)f2bf(w1[1]);
      f[6] = (short)f2bf(w1[2]); f[7] = (short)f2bf(w1[3]);
      wb[j][kk] = f;
    }
  }

  const float* tbase = temps + (size_t)n * (TLEN * FD);
  const int*   pbase = perm + n * NWIN;

  // staging roles: thread -> (row 0..15, seg 0..15), 8 floats per thread
  const int srow = tid >> 4;
  const int sseg = tid & 15;

  // ---- stage tile 0 ----
  {
    const int aw = pbase[s0 + srow] & (NWIN - 1);
    const float* src = tbase + (size_t)aw * KD + sseg * 8;
    f32x4 v0 = *(const f32x4*)src;
    f32x4 v1 = *(const f32x4*)(src + 4);
    u32x4 pk;
    pk[0] = pack2(v0[0], v0[1]); pk[1] = pack2(v0[2], v0[3]);
    pk[2] = pack2(v1[0], v1[1]); pk[3] = pack2(v1[2], v1[3]);
    *(u32x4*)&Abuf[0][srow][sseg * 8] = pk;
  }
  __syncthreads();

  // issue tile-1 global loads early (hide HBM latency under tile-0 MFMA)
  f32x4 q0, q1;
  {
    const int aw = pbase[s0 + 16 + srow] & (NWIN - 1);
    const float* src = tbase + (size_t)aw * KD + sseg * 8;
    q0 = *(const f32x4*)src;
    q1 = *(const f32x4*)(src + 4);
  }

  const f32x4 zero = {0.f, 0.f, 0.f, 0.f};

  // wave-local epilogue: LDS transpose -> coalesced dwordx4 pos/store
  auto epilogue = [&](int sb, f32x4* acc) {
    #pragma unroll
    for (int j = 0; j < 4; ++j)
      #pragma unroll
      for (int r = 0; r < 4; ++r)
        Ebuf[wv][lhi * 4 + r][j * 16 + l15] = acc[j][r] + bb[j];
    __asm__ volatile("s_waitcnt lgkmcnt(0)" ::: "memory");
    #pragma unroll
    for (int g = 0; g < 4; ++g) {
      const int sr   = g * 4 + lhi;
      const int slot = sb + sr;
      const int wr   = pbase[slot] & (NWIN - 1);
      f32x4 v = *(const f32x4*)&Ebuf[wv][sr][l15 * 4];
      const f32x4 pz = *(const f32x4*)&pos[(size_t)wr * ED + e0 + l15 * 4];
      v = v + pz;
      size_t ob;
      if (slot < NKEEP) ob = OFF_VIS + (size_t)(n * NKEEP + slot) * ED;
      else              ob = OFF_TGT + (size_t)(n * NMASK + (slot - NKEEP)) * ED;
      *(f32x4*)&out[ob + (size_t)(e0 + l15 * 4)] = v;
    }
  };

  // ---- compute tile 0 ----
  f32x4 acc0[4];
  acc0[0] = zero; acc0[1] = zero; acc0[2] = zero; acc0[3] = zero;
  #pragma unroll
  for (int kk = 0; kk < 4; ++kk) {
    const bf16x8 a = *(const bf16x8*)&Abuf[0][l15][kk * 32 + lhi * 8];
    #pragma unroll
    for (int j = 0; j < 4; ++j)
      acc0[j] = __builtin_amdgcn_mfma_f32_16x16x32_bf16(a, wb[j][kk], acc0[j], 0, 0, 0);
  }

  // write tile-1 A into the other buffer
  {
    u32x4 pk;
    pk[0] = pack2(q0[0], q0[1]); pk[1] = pack2(q0[2], q0[3]);
    pk[2] = pack2(q1[0], q1[1]); pk[3] = pack2(q1[2], q1[3]);
    *(u32x4*)&Abuf[1][srow][sseg * 8] = pk;
  }

  epilogue(s0, acc0);
  __syncthreads();

  // ---- compute tile 1 ----
  f32x4 acc1[4];
  acc1[0] = zero; acc1[1] = zero; acc1[2] = zero; acc1[3] = zero;
  #pragma unroll
  for (int kk = 0; kk < 4; ++kk) {
    const bf16x8 a = *(const bf16x8*)&Abuf[1][l15][kk * 32 + lhi * 8];
    #pragma unroll
    for (int j = 0; j < 4; ++j)
      acc1[j] = __builtin_amdgcn_mfma_f32_16x16x32_bf16(a, wb[j][kk], acc1[j], 0, 0, 0);
  }
  epilogue(s0 + 16, acc1);
}

// masked_input[n][j][e] = mask_token[e] + pos_embed[m_idx[n][j]][e]
// one thread = 4 consecutive e (16B load/store)
__global__ __launch_bounds__(256) void masked_kernel(
    const float* __restrict__ mask_token, const float* __restrict__ pos,
    const int* __restrict__ perm, float* __restrict__ out)
{
  const int idx = blockIdx.x * 256 + threadIdx.x;   // N*NMASK*64 total
  const int row = idx >> 6;                          // n*NMASK + j
  const int c4  = (idx & 63) * 4;
  if (row >= NB * NMASK) return;
  const int n = row / NMASK;
  const int j = row - n * NMASK;
  const int m = perm[n * NWIN + NKEEP + j] & (NWIN - 1);
  const f32x4 mt = *(const f32x4*)&mask_token[c4];
  const f32x4 pz = *(const f32x4*)&pos[(size_t)m * ED + c4];
  *(f32x4*)&out[OFF_MSK + (size_t)row * ED + c4] = mt + pz;
}

// v_idx / m_idx as float32 values
__global__ void idx_kernel(const int* __restrict__ perm, float* __restrict__ out)
{
  const int n = blockIdx.x;
  const int s = threadIdx.x;    // 0..511
  const int p = perm[n * NWIN + s] & (NWIN - 1);
  const float v = (float)p;
  if (s < NKEEP) out[OFF_VIDX + (size_t)n * NKEEP + s] = v;
  else           out[OFF_MIDX + (size_t)n * NMASK + (s - NKEEP)] = v;
}

extern "C" void kernel_launch(void* const* d_in, const int* in_sizes, int n_in,
                              void* d_out, int out_size, void* d_ws, size_t ws_size,
                              hipStream_t stream) {
  // Identify inputs by flat size (sizes distinct except b/mask_token; b first).
  int i_temps = 0, i_W = 1, i_b = 2, i_mt = 3, i_pos = 4, i_perm = 5;
  int small[2] = {-1, -1}; int nsmall = 0;
  for (int i = 0; i < n_in; ++i) {
    const int s = in_sizes[i];
    if (s == NB * TLEN * FD)        i_temps = i;
    else if (s == ED * KD)          i_W = i;
    else if (s == 1024 * ED)        i_pos = i;
    else if (s == NB * NWIN)        i_perm = i;
    else if (s == ED && nsmall < 2) small[nsmall++] = i;
  }
  if (nsmall == 2) { i_b = small[0]; i_mt = small[1]; }

  const float* temps      = (const float*)d_in[i_temps];
  const float* W          = (const float*)d_in[i_W];
  const float* b          = (const float*)d_in[i_b];
  const float* mask_token = (const float*)d_in[i_mt];
  const float* pos        = (const float*)d_in[i_pos];
  const int*   perm       = (const int*)d_in[i_perm];
  float* out = (float*)d_out;

  emb_kernel<<<dim3(2048), dim3(256), 0, stream>>>(temps, W, b, pos, perm, out);
  masked_kernel<<<dim3(NB * NMASK * 64 / 256), dim3(256), 0, stream>>>(
      mask_token, pos, perm, out);
  idx_kernel<<<dim3(NB), dim3(NWIN), 0, stream>>>(perm, out);
}

// Round 7
// 41.610 us; speedup vs baseline: 1.6429x; 1.4264x over previous
//
#include <hip/hip_runtime.h>
#include <stdint.h>

// (N,T,F)=(128,8192,8), WS=16, E=256 -> nw=512, keep=205, mask=307
#define NB     128
#define TLEN   8192
#define FD     8
#define KD     128          // WS*F (GEMM K)
#define NWIN   512
#define ED     256
#define NKEEP  205
#define NMASK  307

// float32-element offsets in the concatenated output tuple
#define OFF_VIS  0UL
#define OFF_TGT  6717440UL        // + 128*205*256
#define OFF_MSK  16777216UL       // + 128*307*256
#define OFF_VIDX 26836992UL       // + 128*307*256
#define OFF_MIDX 26863232UL       // + 128*205

#define NTILES  4     // MFMA tiles (of 16 slots) per block
#define SLOTS   64    // slots per block
#define ASTRIDE 136   // ushort per A-tile row (128 + 8 pad)
#define ESTRIDE 68    // float per E row (64 + 4 pad)

typedef __attribute__((ext_vector_type(8))) short bf16x8;
typedef __attribute__((ext_vector_type(4))) float f32x4;
typedef __attribute__((ext_vector_type(4))) unsigned int u32x4;

static __device__ __forceinline__ unsigned short f2bf(float x) {
  union { float f; unsigned int u; } v; v.f = x;
  unsigned int r = v.u + 0x7fffu + ((v.u >> 16) & 1u);   // RNE
  return (unsigned short)(r >> 16);
}
static __device__ __forceinline__ unsigned int pack2(float a, float b) {
  return (unsigned int)f2bf(a) | ((unsigned int)f2bf(b) << 16);
}

// Fully fused: emb (GEMM+bias+pos, scattered to vis/tgt), masked_input, and
// v_idx/m_idx. Block = 256 thr (4 waves), 64 slots (4 MFMA tiles), A-tile
// double-buffered in LDS with 2-tile lookahead, W frags in registers
// (wave owns 64 features), per-block perm slice cached in LDS.
__global__ __launch_bounds__(256) void fused_kernel(
    const float* __restrict__ temps, const float* __restrict__ W,
    const float* __restrict__ b, const float* __restrict__ mask_token,
    const float* __restrict__ pos, const int* __restrict__ perm,
    float* __restrict__ out)
{
  __shared__ __align__(16) unsigned short Abuf[2][16][ASTRIDE];
  __shared__ __align__(16) float Ebuf[4][16][ESTRIDE];
  __shared__ int Pbuf[SLOTS];

  const int tid  = threadIdx.x;
  const int lane = tid & 63;
  const int wv   = tid >> 6;     // 0..3
  const int l15  = lane & 15;
  const int lhi  = lane >> 4;    // 0..3

  const int n  = blockIdx.x >> 3;         // 8 blocks per batch row
  const int s0 = (blockIdx.x & 7) * SLOTS;
  const int e0 = wv * 64;

  // per-block perm slice -> LDS
  if (tid < SLOTS) Pbuf[tid] = perm[n * NWIN + s0 + tid] & (NWIN - 1);

  // W fragments: e = e0+j*16+l15 (B-col), k = kk*32 + lhi*8 + i
  bf16x8 wb[4][4];
  float  bb[4];
  #pragma unroll
  for (int j = 0; j < 4; ++j) {
    const int e = e0 + j * 16 + l15;
    bb[j] = b[e];
    const float* wrow = W + (size_t)e * KD + lhi * 8;
    #pragma unroll
    for (int kk = 0; kk < 4; ++kk) {
      f32x4 w0 = *(const f32x4*)(wrow + kk * 32);
      f32x4 w1 = *(const f32x4*)(wrow + kk * 32 + 4);
      bf16x8 f;
      f[0] = (short)f2bf(w0[0]); f[1] = (short)f2bf(w0[1]);
      f[2] = (short)f2bf(w0[2]); f[3] = (short)f2bf(w0[3]);
      f[4] = (short)f2bf(w1[0]); f[5] = (short)f2bf(w1[1]);
      f[6] = (short)f2bf(w1[2]); f[7] = (short)f2bf(w1[3]);
      wb[j][kk] = f;
    }
  }
  const f32x4 mt4 = *(const f32x4*)&mask_token[e0 + l15 * 4];

  const float* tbase = temps + (size_t)n * (TLEN * FD);

  // staging roles: thread -> (row 0..15, seg 0..15), 8 floats per thread
  const int srow = tid >> 4;
  const int sseg = tid & 15;

  __syncthreads();   // Pbuf ready

  // stage tile 0 -> Abuf[0]
  {
    const float* src = tbase + (size_t)Pbuf[srow] * KD + sseg * 8;
    f32x4 v0 = *(const f32x4*)src;
    f32x4 v1 = *(const f32x4*)(src + 4);
    u32x4 pk;
    pk[0] = pack2(v0[0], v0[1]); pk[1] = pack2(v0[2], v0[3]);
    pk[2] = pack2(v1[0], v1[1]); pk[3] = pack2(v1[2], v1[3]);
    *(u32x4*)&Abuf[0][srow][sseg * 8] = pk;
  }
  // issue tile-1 loads
  f32x4 q0, q1;
  {
    const float* src = tbase + (size_t)Pbuf[16 + srow] * KD + sseg * 8;
    q0 = *(const f32x4*)src;
    q1 = *(const f32x4*)(src + 4);
  }
  __syncthreads();   // Abuf[0] ready

  const f32x4 zero = {0.f, 0.f, 0.f, 0.f};

  for (int t = 0; t < NTILES; ++t) {
    // ---- compute tile t ----
    f32x4 acc[4];
    acc[0] = zero; acc[1] = zero; acc[2] = zero; acc[3] = zero;
    #pragma unroll
    for (int kk = 0; kk < 4; ++kk) {
      const bf16x8 a = *(const bf16x8*)&Abuf[t & 1][l15][kk * 32 + lhi * 8];
      #pragma unroll
      for (int j = 0; j < 4; ++j)
        acc[j] = __builtin_amdgcn_mfma_f32_16x16x32_bf16(a, wb[j][kk], acc[j], 0, 0, 0);
    }

    // pack lookahead tile t+1 into the other buffer
    if (t + 1 < NTILES) {
      u32x4 pk;
      pk[0] = pack2(q0[0], q0[1]); pk[1] = pack2(q0[2], q0[3]);
      pk[2] = pack2(q1[0], q1[1]); pk[3] = pack2(q1[2], q1[3]);
      *(u32x4*)&Abuf[(t + 1) & 1][srow][sseg * 8] = pk;
    }
    // issue global loads for tile t+2
    if (t + 2 < NTILES) {
      const float* src = tbase + (size_t)Pbuf[(t + 2) * 16 + srow] * KD + sseg * 8;
      q0 = *(const f32x4*)src;
      q1 = *(const f32x4*)(src + 4);
    }

    // ---- epilogue tile t (emb + masked + idx) ----
    #pragma unroll
    for (int j = 0; j < 4; ++j)
      #pragma unroll
      for (int r = 0; r < 4; ++r)
        Ebuf[wv][lhi * 4 + r][j * 16 + l15] = acc[j][r] + bb[j];
    __asm__ volatile("s_waitcnt lgkmcnt(0)" ::: "memory");
    #pragma unroll
    for (int g = 0; g < 4; ++g) {
      const int sr   = g * 4 + lhi;
      const int slot = s0 + t * 16 + sr;
      const int wr   = Pbuf[t * 16 + sr];
      f32x4 v = *(const f32x4*)&Ebuf[wv][sr][l15 * 4];
      const f32x4 pz = *(const f32x4*)&pos[(size_t)wr * ED + e0 + l15 * 4];
      v = v + pz;
      if (slot < NKEEP) {
        *(f32x4*)&out[OFF_VIS + (size_t)(n * NKEEP + slot) * ED + e0 + l15 * 4] = v;
        if (l15 == 0 && wv == 0)
          out[OFF_VIDX + (size_t)n * NKEEP + slot] = (float)wr;
      } else {
        const int ms = slot - NKEEP;
        *(f32x4*)&out[OFF_TGT + (size_t)(n * NMASK + ms) * ED + e0 + l15 * 4] = v;
        *(f32x4*)&out[OFF_MSK + (size_t)(n * NMASK + ms) * ED + e0 + l15 * 4] = mt4 + pz;
        if (l15 == 0 && wv == 0)
          out[OFF_MIDX + (size_t)n * NMASK + ms] = (float)wr;
      }
    }
    __syncthreads();
  }
}

extern "C" void kernel_launch(void* const* d_in, const int* in_sizes, int n_in,
                              void* d_out, int out_size, void* d_ws, size_t ws_size,
                              hipStream_t stream) {
  // Identify inputs by flat size (sizes distinct except b/mask_token; b first).
  int i_temps = 0, i_W = 1, i_b = 2, i_mt = 3, i_pos = 4, i_perm = 5;
  int small[2] = {-1, -1}; int nsmall = 0;
  for (int i = 0; i < n_in; ++i) {
    const int s = in_sizes[i];
    if (s == NB * TLEN * FD)        i_temps = i;
    else if (s == ED * KD)          i_W = i;
    else if (s == 1024 * ED)        i_pos = i;
    else if (s == NB * NWIN)        i_perm = i;
    else if (s == ED && nsmall < 2) small[nsmall++] = i;
  }
  if (nsmall == 2) { i_b = small[0]; i_mt = small[1]; }

  const float* temps      = (const float*)d_in[i_temps];
  const float* W          = (const float*)d_in[i_W];
  const float* b          = (const float*)d_in[i_b];
  const float* mask_token = (const float*)d_in[i_mt];
  const float* pos        = (const float*)d_in[i_pos];
  const int*   perm       = (const int*)d_in[i_perm];
  float* out = (float*)d_out;

  fused_kernel<<<dim3(NB * 8), dim3(256), 0, stream>>>(
      temps, W, b, mask_token, pos, perm, out);
}